// Round 11
// baseline (199.722 us; speedup 1.0000x reference)
//
#include <hip/hip_runtime.h>

// HashLoss: contrastive (logsumexp over ln@ln^T/0.2) + 0.5*MSE(H@H^T/128, Tn@Tn^T)
//         + 0.01*mean||logits|-1|
// B=4096. R11: trace identity (R10-verified): distill = sign-weighted Frobenius
// of C = Q^T Q (896x896, K=4096), Q = [H(+-1) | Tn*sqrt128] fp8 e4m3.
// prep materializes QT[896][4096] (LDS transpose, odd-pitch banks) so G-role
// tiles stage row-major -> R9's proven b64-frag fp8 MFMA (no gathers in mega).
// G-role: 28 blocks, full-K, fused local square-sum -> one relaxed atomicAdd.
// S-role: 1024 FULL-square 128x128 ln-gram tiles (no mirror masks).
// NO fences/acquire/release anywhere hot (R4/R8 lesson). 3 dispatches.

typedef __bf16 bf16x8 __attribute__((ext_vector_type(8)));
typedef float f32x4 __attribute__((ext_vector_type(4)));

__device__ __forceinline__ unsigned short f2bf(float f) {
  union { float f; unsigned int u; } v; v.f = f;
  unsigned int u = v.u;
  return (unsigned short)((u + 0x7FFFu + ((u >> 16) & 1u)) >> 16);  // RNE
}

// ---- prep: 32 blocks x 256 threads, 128 rows each.
// Phase A: teacher norms (->LDS), logits->P (bf16), qpart, zero accums.
// Phase B/C x7 groups: quantize fp8 into QL[128][129] then transpose-write QT.
__global__ __launch_bounds__(256) void prep(const float* __restrict__ logits,
                                            const float* __restrict__ hash,
                                            const float* __restrict__ teacher,
                                            unsigned short* __restrict__ P,
                                            unsigned char* __restrict__ QT,
                                            float* __restrict__ qpart,
                                            float* __restrict__ rowexp,
                                            float* __restrict__ possum,
                                            float* __restrict__ cntw,
                                            float* __restrict__ dtot) {
  __shared__ float rnt[128];
  __shared__ unsigned char QL[128 * 129];  // odd pitch: bank-spread col gathers
  const int t = threadIdx.x, wave = t >> 6, lane = t & 63;
  const int r0 = (int)blockIdx.x * 128;

  for (int rr = 0; rr < 32; ++rr) {
    const int rl = wave * 32 + rr, r = r0 + rl;
    float ss = 0.f;
#pragma unroll
    for (int i = 0; i < 12; ++i) {
      const float v = teacher[(size_t)r * 768 + i * 64 + lane];
      ss += v * v;
    }
    const float l0 = logits[(size_t)r * 128 + lane];
    const float l1 = logits[(size_t)r * 128 + 64 + lane];
    float ssl = l0 * l0 + l1 * l1;
    float qv = fabsf(fabsf(l0) - 1.f) + fabsf(fabsf(l1) - 1.f);
#pragma unroll
    for (int off = 1; off < 64; off <<= 1) {
      ss += __shfl_xor(ss, off, 64);
      ssl += __shfl_xor(ssl, off, 64);
      qv += __shfl_xor(qv, off, 64);
    }
    const float rnl = 1.f / fmaxf(sqrtf(ssl), 1e-12f);
    P[(size_t)r * 128 + lane] = f2bf(l0 * rnl);
    P[(size_t)r * 128 + 64 + lane] = f2bf(l1 * rnl);
    if (lane == 0) {
      rnt[rl] = 11.313708498984761f / fmaxf(sqrtf(ss), 1e-12f);  // sqrt(128)/||t||
      qpart[r] = qv;
    }
  }
  if (t < 128) { rowexp[r0 + t] = 0.f; possum[r0 + t] = 0.f; cntw[r0 + t] = 0.f; }
  if (blockIdx.x == 0 && t == 0) *dtot = 0.f;
  __syncthreads();

  for (int g = 0; g < 7; ++g) {
    const int rB = t >> 5, cB = (t & 31) * 4;
    for (int pass = 0; pass < 16; ++pass) {
      const int r = rB + pass * 8;
      if (g == 0) {
        const float4 v = *(const float4*)&hash[(size_t)(r0 + r) * 128 + cB];
        QL[r * 129 + cB + 0] = v.x >= 0.f ? 0x38 : 0xB8;  // +-1.0 e4m3 exact
        QL[r * 129 + cB + 1] = v.y >= 0.f ? 0x38 : 0xB8;
        QL[r * 129 + cB + 2] = v.z >= 0.f ? 0x38 : 0xB8;
        QL[r * 129 + cB + 3] = v.w >= 0.f ? 0x38 : 0xB8;
      } else {
        const float sc = rnt[r];
        const float4 v =
            *(const float4*)&teacher[(size_t)(r0 + r) * 768 + (g - 1) * 128 + cB];
        float vv[4] = {v.x * sc, v.y * sc, v.z * sc, v.w * sc};
#pragma unroll
        for (int k = 0; k < 4; ++k) {
          const int p8 = __builtin_amdgcn_cvt_pk_fp8_f32(vv[k], vv[k], 0, false);
          QL[r * 129 + cB + k] = (unsigned char)(p8 & 0xFF);
        }
      }
    }
    __syncthreads();
    // transpose-write: QT[g*128+c][r0 + seg*16 .. +16]
#pragma unroll
    for (int i = 0; i < 4; ++i) {
      const int idx = t + 256 * i;
      const int cl = idx >> 3, seg = idx & 7;
      unsigned char buf[16];
#pragma unroll
      for (int j = 0; j < 16; ++j) buf[j] = QL[(seg * 16 + j) * 129 + cl];
      *(uint4*)&QT[(size_t)(g * 128 + cl) * 4096 + r0 + seg * 16] = *(uint4*)buf;
    }
    __syncthreads();
  }
}

// Stage 128 rows x 128 BYTES from gA (and gB if offdiag) into LDS bytes
// [0..16K) / [16K..32K). LDS 16B-slot p of row holds global chunk p^(row&7).
#define STAGE_GEN(GA, GB, PITCH)                                               \
  {                                                                            \
    _Pragma("unroll") for (int it = 0; it < 4; ++it) {                         \
      const int task = it * 256 + t;                                           \
      const int row = task >> 3;                                               \
      const int c16 = (task & 7) ^ (row & 7);                                  \
      const unsigned char* gpA = (GA) + (size_t)row * (PITCH) + c16 * 16;      \
      __builtin_amdgcn_global_load_lds(                                        \
          (const __attribute__((address_space(1))) void*)gpA,                  \
          (__attribute__((address_space(3))) void*)&SB[it * 4096 + wave * 1024],\
          16, 0, 0);                                                           \
      if (offdiag) {                                                           \
        const unsigned char* gpB = (GB) + (size_t)row * (PITCH) + c16 * 16;    \
        __builtin_amdgcn_global_load_lds(                                      \
            (const __attribute__((address_space(1))) void*)gpB,                \
            (__attribute__((address_space(3)))                                 \
                 void*)&SB[16384 + it * 4096 + wave * 1024],                   \
            16, 0, 0);                                                         \
      }                                                                        \
    }                                                                          \
  }

// bf16 chunk (64 cols = 2 ksteps), 16 MFMA each. Wave (wy,wx) owns 64x64 quad.
#define MFMA_B()                                                               \
  {                                                                            \
    _Pragma("unroll") for (int ks = 0; ks < 2; ++ks) {                         \
      const int ph = ((ks * 4 + qd) ^ (l15 & 7)) * 16;                         \
      bf16x8 af[4], bfr[4];                                                    \
      _Pragma("unroll") for (int rt = 0; rt < 4; ++rt)                         \
          af[rt] = *(const bf16x8*)&SB[(wy * 64 + rt * 16 + l15) * 128 + ph];  \
      _Pragma("unroll") for (int ct = 0; ct < 4; ++ct)                         \
          bfr[ct] = *(const bf16x8*)&SB[boffB +                                \
                                        (wx * 64 + ct * 16 + l15) * 128 + ph]; \
      _Pragma("unroll") for (int rt = 0; rt < 4; ++rt)                         \
          _Pragma("unroll") for (int ct = 0; ct < 4; ++ct) acc[rt][ct] =       \
          __builtin_amdgcn_mfma_f32_16x16x32_bf16(af[rt], bfr[ct],             \
                                                  acc[rt][ct], 0, 0, 0);       \
    }                                                                          \
  }

// fp8 chunk (128 cols = 4 ksteps), 16 MFMA each; 8B frags.
#define MFMA_Q()                                                               \
  {                                                                            \
    _Pragma("unroll") for (int ks = 0; ks < 4; ++ks) {                         \
      const int g0 = ks * 4 + qd;                                              \
      const int ph = ((g0 >> 1) ^ (l15 & 7)) * 16 + (g0 & 1) * 8;              \
      long af[4], bfr[4];                                                      \
      _Pragma("unroll") for (int rt = 0; rt < 4; ++rt)                         \
          af[rt] = *(const long*)&SB[(wy * 64 + rt * 16 + l15) * 128 + ph];    \
      _Pragma("unroll") for (int ct = 0; ct < 4; ++ct)                         \
          bfr[ct] = *(const long*)&SB[boffB +                                  \
                                      (wx * 64 + ct * 16 + l15) * 128 + ph];   \
      _Pragma("unroll") for (int rt = 0; rt < 4; ++rt)                         \
          _Pragma("unroll") for (int ct = 0; ct < 4; ++ct) acc[rt][ct] =       \
          __builtin_amdgcn_mfma_f32_16x16x32_fp8_fp8(af[rt], bfr[ct],          \
                                                     acc[rt][ct], 0, 0, 0);    \
    }                                                                          \
  }

__global__ __launch_bounds__(256, 3) void mega(const unsigned short* __restrict__ P,
                                               const unsigned char* __restrict__ QT,
                                               const void* __restrict__ mask,
                                               float* __restrict__ rowexp,
                                               float* __restrict__ possum,
                                               float* __restrict__ cntw,
                                               float* __restrict__ dtot) {
  __shared__ __align__(16) unsigned char SB[32768];  // A @0, B @16384
  __shared__ float redrow[128][2], red4[4];

  const int t = threadIdx.x;
  const int wave = t >> 6, lane = t & 63;
  const int qd = lane >> 4, l15 = lane & 15;
  const int wy = wave >> 1, wx = wave & 1;
  const int b = (int)blockIdx.x;

  f32x4 acc[4][4];
#pragma unroll
  for (int rt = 0; rt < 4; ++rt)
#pragma unroll
    for (int ct = 0; ct < 4; ++ct) acc[rt][ct] = {0.f, 0.f, 0.f, 0.f};

  if (b < 28) {
    // ---- G-role: C = Q^T Q tile (I,J) from QT, full K=4096 (32 chunks) ----
    int I = 0, rem = b;
    while (rem >= 7 - I) { rem -= 7 - I; ++I; }
    const int J = I + rem;
    const bool offdiag = (I != J);
    const int boffB = offdiag ? 16384 : 0;
    const unsigned char* QA = QT + (size_t)I * 128 * 4096;
    const unsigned char* QB = QT + (size_t)J * 128 * 4096;
    for (int kc = 0; kc < 32; ++kc) {
      __syncthreads();
      STAGE_GEN(QA + kc * 128, QB + kc * 128, 4096);
      __syncthreads();
      MFMA_Q();
    }
    // fused sign-weighted Frobenius (C/D lane layout irrelevant for a sum)
    float dsum = 0.f;
#pragma unroll
    for (int rt = 0; rt < 4; ++rt)
#pragma unroll
      for (int ct = 0; ct < 4; ++ct)
#pragma unroll
        for (int i = 0; i < 4; ++i) dsum += acc[rt][ct][i] * acc[rt][ct][i];
#pragma unroll
    for (int off = 1; off < 64; off <<= 1) dsum += __shfl_xor(dsum, off, 64);
    if (lane == 0) red4[wave] = dsum;
    __syncthreads();
    if (t == 0) {
      const float mult = (I == J ? 1.f : 2.f) *
                         (((I == 0) == (J == 0)) ? 1.f : -1.f);
      atomicAdd(dtot, mult * (red4[0] + red4[1] + red4[2] + red4[3]));
    }
  } else {
    // ---- S-role: ln gram (bf16), FULL-square 128x128 tile + mask epilogue --
    const int bb = b - 28;
    const int l = (bb & 7) * 128 + (bb >> 3);  // XCD swizzle (1024 = 8*128)
    const int bi = l >> 5, bj = l & 31;
    const int ti = bi * 128, tj = bj * 128;
    const bool offdiag = (bi != bj);           // diag tile: B = A (boffB 0)
    const int boffB = offdiag ? 16384 : 0;

    const unsigned char* Pa = (const unsigned char*)(P + (size_t)ti * 128);
    const unsigned char* Pb = (const unsigned char*)(P + (size_t)tj * 128);
    for (int kc = 0; kc < 2; ++kc) {
      __syncthreads();
      STAGE_GEN(Pa + kc * 128, Pb + kc * 128, 256);
      __syncthreads();
      MFMA_B();
    }

    // ---- mask row-tile -> LDS (direct rows only; full square = no mirror) --
    __syncthreads();
    unsigned char* MD = SB;  // [mrow][ncol], 16KB
    const bool is_byte = ((const unsigned char*)mask)[4097] != 0;
    if (is_byte) {
      const unsigned char* m8d = (const unsigned char*)mask + (size_t)ti * 4096 + tj;
#pragma unroll
      for (int it = 0; it < 4; ++it) {
        const int task = it * 256 + t;
        const int row = task >> 3, seg = task & 7;
        __builtin_amdgcn_global_load_lds(
            (const __attribute__((address_space(1))) void*)
                (m8d + (size_t)row * 4096 + seg * 16),
            (__attribute__((address_space(3))) void*)&MD[it * 4096 + wave * 1024],
            16, 0, 0);
      }
    } else {
      const unsigned int* m32 = (const unsigned int*)mask;
#pragma unroll
      for (int it = 0; it < 16; ++it) {
        const int task = it * 256 + t;
        const int row = task >> 5, seg = task & 31;
        const uint4 v = *(const uint4*)&m32[(size_t)(ti + row) * 4096 + tj + seg * 4];
        uchar4 pk;
        pk.x = v.x ? 1 : 0; pk.y = v.y ? 1 : 0;
        pk.z = v.z ? 1 : 0; pk.w = v.w ? 1 : 0;
        *(uchar4*)&MD[row * 128 + seg * 4] = pk;
      }
    }
    __syncthreads();

#pragma unroll
    for (int rt = 0; rt < 4; ++rt) {
#pragma unroll
      for (int r = 0; r < 4; ++r) {
        const int mrow = wy * 64 + rt * 16 + qd * 4 + r;  // C/D: row=qd*4+reg
        const int m = ti + mrow;
        float se = 0.f;
#pragma unroll
        for (int ct = 0; ct < 4; ++ct) {
          const int ncol = wx * 64 + ct * 16 + l15;       // C/D: col=lane&15
          const int n = tj + ncol;
          const float sim = acc[rt][ct][r] * 5.0f;        // /TEMPERATURE
          const float e = __expf(sim);
          if (m != n) se += e;                            // diag excluded
          if (MD[mrow * 128 + ncol]) {                    // sparse positives
            atomicAdd(&possum[m], sim);
            atomicAdd(&cntw[m], 1.0f);
          }
        }
#pragma unroll
        for (int off = 1; off < 16; off <<= 1) se += __shfl_xor(se, off, 64);
        if (l15 == 0) redrow[mrow][wx] = se;
      }
    }
    __syncthreads();
    if (t < 128) atomicAdd(&rowexp[ti + t], redrow[t][0] + redrow[t][1]);
  }
}

__global__ __launch_bounds__(1024) void finalize(const float* __restrict__ rowexp,
                                                 const float* __restrict__ possum,
                                                 const float* __restrict__ cnt,
                                                 const float* __restrict__ qpart,
                                                 const float* __restrict__ dtot,
                                                 float* __restrict__ out) {
  const int t = threadIdx.x;
  const int wave = t >> 6, lane = t & 63;
  float c = 0.f, q = 0.f;
  for (int m = t; m < 4096; m += 1024) {
    c += logf(rowexp[m]) - possum[m] / fmaxf(cnt[m], 1.0f);
    q += qpart[m];
  }
#pragma unroll
  for (int off = 1; off < 64; off <<= 1) {
    c += __shfl_xor(c, off, 64);
    q += __shfl_xor(q, off, 64);
  }
  __shared__ float sc[16], sq[16];
  if (lane == 0) { sc[wave] = c; sq[wave] = q; }
  __syncthreads();
  if (t == 0) {
    float C = 0.f, Q = 0.f;
    for (int i = 0; i < 16; ++i) { C += sc[i]; Q += sq[i]; }
    // dtot = 16384 * B^2 * loss_distill -> 0.5 * dtot / (4096^2 * 16384)
    out[0] = C * (1.0f / 4096.0f) + 0.5f * (dtot[0] * 3.6379788e-12f) +
             0.01f * (Q * (1.0f / 524288.0f));
  }
}

extern "C" void kernel_launch(void* const* d_in, const int* in_sizes, int n_in,
                              void* d_out, int out_size, void* d_ws, size_t ws_size,
                              hipStream_t stream) {
  const float* logits = (const float*)d_in[0];
  const float* hash = (const float*)d_in[1];
  const float* teacher = (const float*)d_in[2];
  const void* mask = d_in[3];
  float* out = (float*)d_out;

  char* ws = (char*)d_ws;
  float* rowexp = (float*)(ws + 0);
  float* possum = (float*)(ws + 16384);
  float* cntw = (float*)(ws + 32768);
  float* qpart = (float*)(ws + 49152);
  float* dtot = (float*)(ws + 65536);
  unsigned short* P = (unsigned short*)(ws + 98304);         // 4096x128 bf16 = 1 MB
  unsigned char* QT = (unsigned char*)(ws + 98304 + 1048576);  // 896x4096 fp8 = 3.5 MB

  prep<<<32, 256, 0, stream>>>(logits, hash, teacher, P, QT, qpart, rowexp,
                               possum, cntw, dtot);
  mega<<<1052, 256, 0, stream>>>(P, QT, mask, rowexp, possum, cntw, dtot);
  finalize<<<1, 1024, 0, stream>>>(rowexp, possum, cntw, qpart, dtot, out);
}

// Round 12
// 155.122 us; speedup vs baseline: 1.2875x; 1.2875x over previous
//
#include <hip/hip_runtime.h>

// HashLoss: contrastive (logsumexp over ln@ln^T/0.2) + 0.5*MSE(H@H^T/128, Tn@Tn^T)
//         + 0.01*mean||logits|-1|
// B=4096. R12 = R11 mega/finalize (trace-identity distill via C=Q^T Q from
// materialized QT; S-role full-square ln-gram) + re-parallelized prep:
// 256 blocks x 16 rows (R11's 32-block prep was occupancy-starved: 61us, 1.3%).
// NO fences/acquire/release in hot kernels (R4/R8 lesson). 3 dispatches.

typedef __bf16 bf16x8 __attribute__((ext_vector_type(8)));
typedef float f32x4 __attribute__((ext_vector_type(4)));

__device__ __forceinline__ unsigned short f2bf(float f) {
  union { float f; unsigned int u; } v; v.f = f;
  unsigned int u = v.u;
  return (unsigned short)((u + 0x7FFFu + ((u >> 16) & 1u)) >> 16);  // RNE
}

// ---- prep: 256 blocks x 256 threads, 16 rows each.
// A: norms -> P bf16, qpart, rnt (wave per row, 4 serial rows/wave).
// B: quantize 16x896 fp8 slab into QL (odd pitch 897).
// C: 896 column-gathers -> 16B stores to QT[c][r0..r0+16).
__global__ __launch_bounds__(256) void prep(const float* __restrict__ logits,
                                            const float* __restrict__ hash,
                                            const float* __restrict__ teacher,
                                            unsigned short* __restrict__ P,
                                            unsigned char* __restrict__ QT,
                                            float* __restrict__ qpart,
                                            float* __restrict__ rowexp,
                                            float* __restrict__ possum,
                                            float* __restrict__ cntw,
                                            float* __restrict__ dtot) {
  __shared__ float rnt[16];
  __shared__ unsigned char QL[16 * 897];  // odd pitch: bank-spread col gathers
  const int t = threadIdx.x, wave = t >> 6, lane = t & 63;
  const int r0 = (int)blockIdx.x * 16;

#pragma unroll
  for (int rr = 0; rr < 4; ++rr) {
    const int rl = wave * 4 + rr, r = r0 + rl;
    float ss = 0.f;
#pragma unroll
    for (int i = 0; i < 12; ++i) {
      const float v = teacher[(size_t)r * 768 + i * 64 + lane];
      ss += v * v;
    }
    const float l0 = logits[(size_t)r * 128 + lane];
    const float l1 = logits[(size_t)r * 128 + 64 + lane];
    float ssl = l0 * l0 + l1 * l1;
    float qv = fabsf(fabsf(l0) - 1.f) + fabsf(fabsf(l1) - 1.f);
#pragma unroll
    for (int off = 1; off < 64; off <<= 1) {
      ss += __shfl_xor(ss, off, 64);
      ssl += __shfl_xor(ssl, off, 64);
      qv += __shfl_xor(qv, off, 64);
    }
    const float rnl = 1.f / fmaxf(sqrtf(ssl), 1e-12f);
    P[(size_t)r * 128 + lane] = f2bf(l0 * rnl);
    P[(size_t)r * 128 + 64 + lane] = f2bf(l1 * rnl);
    if (lane == 0) {
      rnt[rl] = 11.313708498984761f / fmaxf(sqrtf(ss), 1e-12f);  // sqrt128/||t||
      qpart[r] = qv;
    }
  }
  if (t < 16) { rowexp[r0 + t] = 0.f; possum[r0 + t] = 0.f; cntw[r0 + t] = 0.f; }
  if (blockIdx.x == 0 && t == 0) *dtot = 0.f;
  __syncthreads();

  // B: task = (row, 16-col block). 16 rows x 56 blocks = 896 tasks.
#pragma unroll
  for (int it = 0; it < 4; ++it) {
    const int task = it * 256 + t;
    if (task < 896) {
      const int r = task / 56, cb = task % 56;
      const int r_g = r0 + r;
      unsigned char* dst = &QL[r * 897 + cb * 16];
      if (cb < 8) {  // hash cols 0..127: exact +-1.0 e4m3
        const float4 v0 = *(const float4*)&hash[(size_t)r_g * 128 + cb * 16];
        const float4 v1 = *(const float4*)&hash[(size_t)r_g * 128 + cb * 16 + 4];
        const float4 v2 = *(const float4*)&hash[(size_t)r_g * 128 + cb * 16 + 8];
        const float4 v3 = *(const float4*)&hash[(size_t)r_g * 128 + cb * 16 + 12];
        const float vv[16] = {v0.x, v0.y, v0.z, v0.w, v1.x, v1.y, v1.z, v1.w,
                              v2.x, v2.y, v2.z, v2.w, v3.x, v3.y, v3.z, v3.w};
#pragma unroll
        for (int k = 0; k < 16; ++k) dst[k] = vv[k] >= 0.f ? 0x38 : 0xB8;
      } else {  // teacher cols: * sqrt(128)/||t||, fp8 e4m3
        const float sc = rnt[r];
        const int c0 = cb * 16 - 128;
        const float4 v0 = *(const float4*)&teacher[(size_t)r_g * 768 + c0];
        const float4 v1 = *(const float4*)&teacher[(size_t)r_g * 768 + c0 + 4];
        const float4 v2 = *(const float4*)&teacher[(size_t)r_g * 768 + c0 + 8];
        const float4 v3 = *(const float4*)&teacher[(size_t)r_g * 768 + c0 + 12];
        const float vv[16] = {v0.x, v0.y, v0.z, v0.w, v1.x, v1.y, v1.z, v1.w,
                              v2.x, v2.y, v2.z, v2.w, v3.x, v3.y, v3.z, v3.w};
#pragma unroll
        for (int k = 0; k < 16; ++k) {
          const int p8 = __builtin_amdgcn_cvt_pk_fp8_f32(vv[k] * sc, vv[k] * sc,
                                                         0, false);
          dst[k] = (unsigned char)(p8 & 0xFF);
        }
      }
    }
  }
  __syncthreads();

  // C: transpose-write. Thread owns column c: gather 16 rows, one 16B store.
#pragma unroll
  for (int i = 0; i < 4; ++i) {
    const int c = t + 256 * i;
    if (c < 896) {
      unsigned char buf[16];
#pragma unroll
      for (int j = 0; j < 16; ++j) buf[j] = QL[j * 897 + c];
      *(uint4*)&QT[(size_t)c * 4096 + r0] = *(uint4*)buf;
    }
  }
}

// Stage 128 rows x 128 BYTES from gA (and gB if offdiag) into LDS bytes
// [0..16K) / [16K..32K). LDS 16B-slot p of row holds global chunk p^(row&7).
#define STAGE_GEN(GA, GB, PITCH)                                               \
  {                                                                            \
    _Pragma("unroll") for (int it = 0; it < 4; ++it) {                         \
      const int task = it * 256 + t;                                           \
      const int row = task >> 3;                                               \
      const int c16 = (task & 7) ^ (row & 7);                                  \
      const unsigned char* gpA = (GA) + (size_t)row * (PITCH) + c16 * 16;      \
      __builtin_amdgcn_global_load_lds(                                        \
          (const __attribute__((address_space(1))) void*)gpA,                  \
          (__attribute__((address_space(3))) void*)&SB[it * 4096 + wave * 1024],\
          16, 0, 0);                                                           \
      if (offdiag) {                                                           \
        const unsigned char* gpB = (GB) + (size_t)row * (PITCH) + c16 * 16;    \
        __builtin_amdgcn_global_load_lds(                                      \
            (const __attribute__((address_space(1))) void*)gpB,                \
            (__attribute__((address_space(3)))                                 \
                 void*)&SB[16384 + it * 4096 + wave * 1024],                   \
            16, 0, 0);                                                         \
      }                                                                        \
    }                                                                          \
  }

// bf16 chunk (64 cols = 2 ksteps), 16 MFMA each. Wave (wy,wx) owns 64x64 quad.
#define MFMA_B()                                                               \
  {                                                                            \
    _Pragma("unroll") for (int ks = 0; ks < 2; ++ks) {                         \
      const int ph = ((ks * 4 + qd) ^ (l15 & 7)) * 16;                         \
      bf16x8 af[4], bfr[4];                                                    \
      _Pragma("unroll") for (int rt = 0; rt < 4; ++rt)                         \
          af[rt] = *(const bf16x8*)&SB[(wy * 64 + rt * 16 + l15) * 128 + ph];  \
      _Pragma("unroll") for (int ct = 0; ct < 4; ++ct)                         \
          bfr[ct] = *(const bf16x8*)&SB[boffB +                                \
                                        (wx * 64 + ct * 16 + l15) * 128 + ph]; \
      _Pragma("unroll") for (int rt = 0; rt < 4; ++rt)                         \
          _Pragma("unroll") for (int ct = 0; ct < 4; ++ct) acc[rt][ct] =       \
          __builtin_amdgcn_mfma_f32_16x16x32_bf16(af[rt], bfr[ct],             \
                                                  acc[rt][ct], 0, 0, 0);       \
    }                                                                          \
  }

// fp8 chunk (128 cols = 4 ksteps), 16 MFMA each; 8B frags.
#define MFMA_Q()                                                               \
  {                                                                            \
    _Pragma("unroll") for (int ks = 0; ks < 4; ++ks) {                         \
      const int g0 = ks * 4 + qd;                                              \
      const int ph = ((g0 >> 1) ^ (l15 & 7)) * 16 + (g0 & 1) * 8;              \
      long af[4], bfr[4];                                                      \
      _Pragma("unroll") for (int rt = 0; rt < 4; ++rt)                         \
          af[rt] = *(const long*)&SB[(wy * 64 + rt * 16 + l15) * 128 + ph];    \
      _Pragma("unroll") for (int ct = 0; ct < 4; ++ct)                         \
          bfr[ct] = *(const long*)&SB[boffB +                                  \
                                      (wx * 64 + ct * 16 + l15) * 128 + ph];   \
      _Pragma("unroll") for (int rt = 0; rt < 4; ++rt)                         \
          _Pragma("unroll") for (int ct = 0; ct < 4; ++ct) acc[rt][ct] =       \
          __builtin_amdgcn_mfma_f32_16x16x32_fp8_fp8(af[rt], bfr[ct],          \
                                                     acc[rt][ct], 0, 0, 0);    \
    }                                                                          \
  }

__global__ __launch_bounds__(256, 3) void mega(const unsigned short* __restrict__ P,
                                               const unsigned char* __restrict__ QT,
                                               const void* __restrict__ mask,
                                               float* __restrict__ rowexp,
                                               float* __restrict__ possum,
                                               float* __restrict__ cntw,
                                               float* __restrict__ dtot) {
  __shared__ __align__(16) unsigned char SB[32768];  // A @0, B @16384
  __shared__ float redrow[128][2], red4[4];

  const int t = threadIdx.x;
  const int wave = t >> 6, lane = t & 63;
  const int qd = lane >> 4, l15 = lane & 15;
  const int wy = wave >> 1, wx = wave & 1;
  const int b = (int)blockIdx.x;

  f32x4 acc[4][4];
#pragma unroll
  for (int rt = 0; rt < 4; ++rt)
#pragma unroll
    for (int ct = 0; ct < 4; ++ct) acc[rt][ct] = {0.f, 0.f, 0.f, 0.f};

  if (b < 28) {
    // ---- G-role: C = Q^T Q tile (I,J) from QT, full K=4096 (32 chunks) ----
    int I = 0, rem = b;
    while (rem >= 7 - I) { rem -= 7 - I; ++I; }
    const int J = I + rem;
    const bool offdiag = (I != J);
    const int boffB = offdiag ? 16384 : 0;
    const unsigned char* QA = QT + (size_t)I * 128 * 4096;
    const unsigned char* QB = QT + (size_t)J * 128 * 4096;
    for (int kc = 0; kc < 32; ++kc) {
      __syncthreads();
      STAGE_GEN(QA + kc * 128, QB + kc * 128, 4096);
      __syncthreads();
      MFMA_Q();
    }
    // fused sign-weighted Frobenius (C/D lane layout irrelevant for a sum)
    float dsum = 0.f;
#pragma unroll
    for (int rt = 0; rt < 4; ++rt)
#pragma unroll
      for (int ct = 0; ct < 4; ++ct)
#pragma unroll
        for (int i = 0; i < 4; ++i) dsum += acc[rt][ct][i] * acc[rt][ct][i];
#pragma unroll
    for (int off = 1; off < 64; off <<= 1) dsum += __shfl_xor(dsum, off, 64);
    if (lane == 0) red4[wave] = dsum;
    __syncthreads();
    if (t == 0) {
      const float mult = (I == J ? 1.f : 2.f) *
                         (((I == 0) == (J == 0)) ? 1.f : -1.f);
      atomicAdd(dtot, mult * (red4[0] + red4[1] + red4[2] + red4[3]));
    }
  } else {
    // ---- S-role: ln gram (bf16), FULL-square 128x128 tile + mask epilogue --
    const int bb = b - 28;
    const int l = (bb & 7) * 128 + (bb >> 3);  // XCD swizzle (1024 = 8*128)
    const int bi = l >> 5, bj = l & 31;
    const int ti = bi * 128, tj = bj * 128;
    const bool offdiag = (bi != bj);           // diag tile: B = A (boffB 0)
    const int boffB = offdiag ? 16384 : 0;

    const unsigned char* Pa = (const unsigned char*)(P + (size_t)ti * 128);
    const unsigned char* Pb = (const unsigned char*)(P + (size_t)tj * 128);
    for (int kc = 0; kc < 2; ++kc) {
      __syncthreads();
      STAGE_GEN(Pa + kc * 128, Pb + kc * 128, 256);
      __syncthreads();
      MFMA_B();
    }

    // ---- mask row-tile -> LDS (direct rows only; full square = no mirror) --
    __syncthreads();
    unsigned char* MD = SB;  // [mrow][ncol], 16KB
    const bool is_byte = ((const unsigned char*)mask)[4097] != 0;
    if (is_byte) {
      const unsigned char* m8d = (const unsigned char*)mask + (size_t)ti * 4096 + tj;
#pragma unroll
      for (int it = 0; it < 4; ++it) {
        const int task = it * 256 + t;
        const int row = task >> 3, seg = task & 7;
        __builtin_amdgcn_global_load_lds(
            (const __attribute__((address_space(1))) void*)
                (m8d + (size_t)row * 4096 + seg * 16),
            (__attribute__((address_space(3))) void*)&MD[it * 4096 + wave * 1024],
            16, 0, 0);
      }
    } else {
      const unsigned int* m32 = (const unsigned int*)mask;
#pragma unroll
      for (int it = 0; it < 16; ++it) {
        const int task = it * 256 + t;
        const int row = task >> 5, seg = task & 31;
        const uint4 v = *(const uint4*)&m32[(size_t)(ti + row) * 4096 + tj + seg * 4];
        uchar4 pk;
        pk.x = v.x ? 1 : 0; pk.y = v.y ? 1 : 0;
        pk.z = v.z ? 1 : 0; pk.w = v.w ? 1 : 0;
        *(uchar4*)&MD[row * 128 + seg * 4] = pk;
      }
    }
    __syncthreads();

#pragma unroll
    for (int rt = 0; rt < 4; ++rt) {
#pragma unroll
      for (int r = 0; r < 4; ++r) {
        const int mrow = wy * 64 + rt * 16 + qd * 4 + r;  // C/D: row=qd*4+reg
        const int m = ti + mrow;
        float se = 0.f;
#pragma unroll
        for (int ct = 0; ct < 4; ++ct) {
          const int ncol = wx * 64 + ct * 16 + l15;       // C/D: col=lane&15
          const int n = tj + ncol;
          const float sim = acc[rt][ct][r] * 5.0f;        // /TEMPERATURE
          const float e = __expf(sim);
          if (m != n) se += e;                            // diag excluded
          if (MD[mrow * 128 + ncol]) {                    // sparse positives
            atomicAdd(&possum[m], sim);
            atomicAdd(&cntw[m], 1.0f);
          }
        }
#pragma unroll
        for (int off = 1; off < 16; off <<= 1) se += __shfl_xor(se, off, 64);
        if (l15 == 0) redrow[mrow][wx] = se;
      }
    }
    __syncthreads();
    if (t < 128) atomicAdd(&rowexp[ti + t], redrow[t][0] + redrow[t][1]);
  }
}

__global__ __launch_bounds__(1024) void finalize(const float* __restrict__ rowexp,
                                                 const float* __restrict__ possum,
                                                 const float* __restrict__ cnt,
                                                 const float* __restrict__ qpart,
                                                 const float* __restrict__ dtot,
                                                 float* __restrict__ out) {
  const int t = threadIdx.x;
  const int wave = t >> 6, lane = t & 63;
  float c = 0.f, q = 0.f;
  for (int m = t; m < 4096; m += 1024) {
    c += logf(rowexp[m]) - possum[m] / fmaxf(cnt[m], 1.0f);
    q += qpart[m];
  }
#pragma unroll
  for (int off = 1; off < 64; off <<= 1) {
    c += __shfl_xor(c, off, 64);
    q += __shfl_xor(q, off, 64);
  }
  __shared__ float sc[16], sq[16];
  if (lane == 0) { sc[wave] = c; sq[wave] = q; }
  __syncthreads();
  if (t == 0) {
    float C = 0.f, Q = 0.f;
    for (int i = 0; i < 16; ++i) { C += sc[i]; Q += sq[i]; }
    // dtot = 16384 * B^2 * loss_distill -> 0.5 * dtot / (4096^2 * 16384)
    out[0] = C * (1.0f / 4096.0f) + 0.5f * (dtot[0] * 3.6379788e-12f) +
             0.01f * (Q * (1.0f / 524288.0f));
  }
}

extern "C" void kernel_launch(void* const* d_in, const int* in_sizes, int n_in,
                              void* d_out, int out_size, void* d_ws, size_t ws_size,
                              hipStream_t stream) {
  const float* logits = (const float*)d_in[0];
  const float* hash = (const float*)d_in[1];
  const float* teacher = (const float*)d_in[2];
  const void* mask = d_in[3];
  float* out = (float*)d_out;

  char* ws = (char*)d_ws;
  float* rowexp = (float*)(ws + 0);
  float* possum = (float*)(ws + 16384);
  float* cntw = (float*)(ws + 32768);
  float* qpart = (float*)(ws + 49152);
  float* dtot = (float*)(ws + 65536);
  unsigned short* P = (unsigned short*)(ws + 98304);         // 4096x128 bf16 = 1 MB
  unsigned char* QT = (unsigned char*)(ws + 98304 + 1048576);  // 896x4096 fp8 = 3.5 MB

  prep<<<256, 256, 0, stream>>>(logits, hash, teacher, P, QT, qpart, rowexp,
                                possum, cntw, dtot);
  mega<<<1052, 256, 0, stream>>>(P, QT, mask, rowexp, possum, cntw, dtot);
  finalize<<<1, 1024, 0, stream>>>(rowexp, possum, cntw, qpart, dtot, out);
}